// Round 14
// baseline (1116.100 us; speedup 1.0000x reference)
//
#include <hip/hip_runtime.h>
#include <hip/hip_bf16.h>
#include <math.h>

typedef unsigned short u16;
typedef __attribute__((ext_vector_type(8))) short s16x8;
typedef __attribute__((ext_vector_type(8))) unsigned short u16x8;
typedef __attribute__((ext_vector_type(4))) float f32x4;

#define SCALE 0.083333333333333329f   // 1/sqrt(144)
#define LDO 4128                      // padded Ob row stride (breaks 8KB pow2 aliasing)

__device__ __forceinline__ u16 f2bf(float f) {
    unsigned u = __float_as_uint(f);
    unsigned r = 0x7fffu + ((u >> 16) & 1u);
    return (u16)((u + r) >> 16);
}
__device__ __forceinline__ float bf2f(u16 v) {
    return __uint_as_float(((unsigned)v) << 16);
}

// ---------------- cast fp32 -> bf16 (vectorized; used for x only) ----------------
__global__ __launch_bounds__(256) void cast_kernel(const float* __restrict__ in,
                                                   u16* __restrict__ out) {
    size_t i = ((size_t)blockIdx.x * 256 + threadIdx.x) * 4;
    float4 v = *(const float4*)(in + i);
    ushort4 o;
    o.x = f2bf(v.x); o.y = f2bf(v.y); o.z = f2bf(v.z); o.w = f2bf(v.w);
    *(ushort4*)(out + i) = o;
}

// ---------------- rope cos/sin table ----------------
__global__ __launch_bounds__(256) void rope_table_kernel(float* __restrict__ cosT,
                                                         float* __restrict__ sinT) {
    int idx = blockIdx.x * 256 + threadIdx.x;   // L*64
    int i = idx & 63, pos = idx >> 6;
    float inv = __expf(-((float)i / 64.0f) * 9.210340371976184f); // 10000^(-i/64)
    float ang = (float)pos * inv;
    cosT[idx] = cosf(ang);
    sinT[idx] = sinf(ang);
}

// ---------------- rope for Q from fused T16 [2048][8192] bf16, cols 0..4095 ----------------
__global__ __launch_bounds__(256) void rope_q_kernel(const u16* __restrict__ T16,
                                                     u16* __restrict__ Qb,
                                                     const float* __restrict__ cosT,
                                                     const float* __restrict__ sinT) {
    int idx = blockIdx.x * 256 + threadIdx.x;   // L*32*64
    int i = idx & 63;
    int head = (idx >> 6) & 31;
    int pos = idx >> 11;
    size_t rbase = (size_t)pos * 8192 + head * 128 + i;
    float t1 = bf2f(T16[rbase]), t2 = bf2f(T16[rbase + 64]);
    float c = cosT[(pos << 6) + i], s = sinT[(pos << 6) + i];
    size_t wbase = (size_t)pos * 4096 + head * 128 + i;
    Qb[wbase]      = f2bf((t1 * c - t2 * s) * SCALE);
    Qb[wbase + 64] = f2bf((t2 * c + t1 * s) * SCALE);
}

// ---------------- rope for K from fused T16, cols 4096..6143 ----------------
__global__ __launch_bounds__(256) void rope_k_kernel(const u16* __restrict__ T16,
                                                     u16* __restrict__ Kb,
                                                     const float* __restrict__ cosT,
                                                     const float* __restrict__ sinT) {
    int idx = blockIdx.x * 256 + threadIdx.x;   // L*16*64
    int i = idx & 63;
    int head = (idx >> 6) & 15;
    int pos = idx >> 10;
    size_t rbase = (size_t)pos * 8192 + 4096 + head * 128 + i;
    float t1 = bf2f(T16[rbase]), t2 = bf2f(T16[rbase + 64]);
    float c = cosT[(pos << 6) + i], s = sinT[(pos << 6) + i];
    size_t wbase = (size_t)pos * 2048 + head * 128 + i;
    Kb[wbase]      = f2bf(t1 * c - t2 * s);
    Kb[wbase + 64] = f2bf(t2 * c + t1 * s);
}

// ---------------- V transpose from fused T16, cols 6144..8191 ----------------
__global__ __launch_bounds__(256) void vtrans_kernel(const u16* __restrict__ T16,
                                                     u16* __restrict__ Vt) {
    __shared__ u16 tile[32][33];
    int bc = (blockIdx.x & 63) << 5;    // col within V block (0..2047)
    int bl = (blockIdx.x >> 6) << 5;    // row (l) tile
    int x = threadIdx.x & 31, y = threadIdx.x >> 5;
    #pragma unroll
    for (int yy = y; yy < 32; yy += 8)
        tile[yy][x] = T16[(size_t)(bl + yy) * 8192 + 6144 + bc + x];
    __syncthreads();
    #pragma unroll
    for (int yy = y; yy < 32; yy += 8)
        Vt[(size_t)(bc + yy) * 2048 + bl + x] = tile[x][yy];
}

// ============ 256x256 8-wave 4-phase GEMM, fused f32->bf16 B staging (t+2 deep) ============
// A: bf16 (lda), global_load_lds, stages for t+1 spread P0:{A0,A1} P1:{A2,A3}.
// B: f32 (ldbf), reg-staged: tile t's top issues 8 dwordx4 for tile t+2 (full ~2-tile
//    HBM cover); cvt+swizzled ds_write of B(t+1) in P3's shadow (the empty phase).
// SINGLE wait per tile: vmcnt(8) at P0 drains [LB8(t+1), A4(t)], keeps LB8(t+2).
// Fragment ds_reads hoisted into the previous phase's shadow (round-13 proven).
// Buffer safety: B(t+1)-writes at t's P3 target buf[nxt] (last read at t-1, safety
// barrier = t's P0); lgkmcnt(0)+sched_barrier before tile-end barrier (rule 18).
// Main loop unrolled x2 (nt even) so rE/rO reg blocks are statically indexed.
#define STAGE_A(buf, ktt, l)                                                            \
    __builtin_amdgcn_global_load_lds(                                                   \
        (const __attribute__((address_space(1))) unsigned int*)(aSrc + (size_t)(ktt) * 64 + (size_t)(l) * 64 * lda), \
        (__attribute__((address_space(3))) unsigned int*)(&lds[buf][0][(l) * 4096 + ldsoff]), 16, 0, 0)

#define LOADB(REG, KTT)                                                                 \
    _Pragma("unroll")                                                                   \
    for (int l = 0; l < 4; ++l) {                                                       \
        const float* p = bSrcF + (size_t)l * 64 * ldbf + (size_t)(KTT) * 64;            \
        REG[l][0] = *(const float4*)p;                                                  \
        REG[l][1] = *(const float4*)(p + 4);                                            \
    }

#define CVTW(REG, BUF)                                                                  \
    _Pragma("unroll")                                                                   \
    for (int l = 0; l < 4; ++l) {                                                       \
        u16x8 pk;                                                                       \
        pk[0] = f2bf(REG[l][0].x); pk[1] = f2bf(REG[l][0].y);                           \
        pk[2] = f2bf(REG[l][0].z); pk[3] = f2bf(REG[l][0].w);                           \
        pk[4] = f2bf(REG[l][1].x); pk[5] = f2bf(REG[l][1].y);                           \
        pk[6] = f2bf(REG[l][1].z); pk[7] = f2bf(REG[l][1].w);                           \
        *(u16x8*)((char*)&lds[BUF][1][0] + l * 8192 + bwb) = pk;                        \
    }

#define GTILE(CUR, NXT, RL, RW, T)                                                      \
  {                                                                                     \
    bool ld2 = ((T) + 2 < nt);                                                          \
    bool stA = ((T) + 1 < nt);                                                          \
    if (ld2) {                                                                          \
        LOADB(RL, (T) + 2);                                                             \
        __builtin_amdgcn_sched_barrier(0);                                              \
        asm volatile("s_waitcnt vmcnt(8)" ::: "memory");                                \
    } else {                                                                            \
        asm volatile("s_waitcnt vmcnt(0)" ::: "memory");                                \
    }                                                                                   \
    __builtin_amdgcn_s_barrier();                                                       \
    const char* Ab = (const char*)&lds[CUR][0][0];                                      \
    const char* Bb = (const char*)&lds[CUR][1][0];                                      \
    int cb0 = (fq * 16) ^ sw;                                                           \
    int cb1 = (64 + fq * 16) ^ sw;                                                      \
    /* phase 0 */                                                                       \
    if (stA) { STAGE_A(NXT, (T) + 1, 0); STAGE_A(NXT, (T) + 1, 1); }                    \
    s16x8 b0[4], a0[4];                                                                 \
    _Pragma("unroll")                                                                   \
    for (int n = 0; n < 4; ++n)                                                         \
        b0[n] = *(const s16x8*)(Bb + (wn * 64 + n * 16 + fr) * 128 + cb0);              \
    _Pragma("unroll")                                                                   \
    for (int m = 0; m < 4; ++m)                                                         \
        a0[m] = *(const s16x8*)(Ab + (wm * 128 + m * 16 + fr) * 128 + cb0);             \
    __builtin_amdgcn_s_setprio(1);                                                      \
    _Pragma("unroll")                                                                   \
    for (int m = 0; m < 4; ++m)                                                         \
        _Pragma("unroll")                                                               \
        for (int n = 0; n < 4; ++n)                                                     \
            acc[m][n] = __builtin_amdgcn_mfma_f32_16x16x32_bf16(a0[m], b0[n], acc[m][n], 0, 0, 0); \
    __builtin_amdgcn_s_setprio(0);                                                      \
    s16x8 a1[4];                                                                        \
    _Pragma("unroll")                                                                   \
    for (int m = 0; m < 4; ++m)                                                         \
        a1[m] = *(const s16x8*)(Ab + (wm * 128 + (4 + m) * 16 + fr) * 128 + cb0);       \
    __builtin_amdgcn_s_barrier();                                                       \
    /* phase 1 */                                                                       \
    if (stA) { STAGE_A(NXT, (T) + 1, 2); STAGE_A(NXT, (T) + 1, 3); }                    \
    __builtin_amdgcn_s_setprio(1);                                                      \
    _Pragma("unroll")                                                                   \
    for (int m = 0; m < 4; ++m)                                                         \
        _Pragma("unroll")                                                               \
        for (int n = 0; n < 4; ++n)                                                     \
            acc[4 + m][n] = __builtin_amdgcn_mfma_f32_16x16x32_bf16(a1[m], b0[n], acc[4 + m][n], 0, 0, 0); \
    __builtin_amdgcn_s_setprio(0);                                                      \
    s16x8 b1[4], a2[4];                                                                 \
    _Pragma("unroll")                                                                   \
    for (int n = 0; n < 4; ++n)                                                         \
        b1[n] = *(const s16x8*)(Bb + (wn * 64 + n * 16 + fr) * 128 + cb1);              \
    _Pragma("unroll")                                                                   \
    for (int m = 0; m < 4; ++m)                                                         \
        a2[m] = *(const s16x8*)(Ab + (wm * 128 + m * 16 + fr) * 128 + cb1);             \
    __builtin_amdgcn_s_barrier();                                                       \
    /* phase 2 */                                                                       \
    __builtin_amdgcn_s_setprio(1);                                                      \
    _Pragma("unroll")                                                                   \
    for (int m = 0; m < 4; ++m)                                                         \
        _Pragma("unroll")                                                               \
        for (int n = 0; n < 4; ++n)                                                     \
            acc[m][n] = __builtin_amdgcn_mfma_f32_16x16x32_bf16(a2[m], b1[n], acc[m][n], 0, 0, 0); \
    __builtin_amdgcn_s_setprio(0);                                                      \
    s16x8 a3[4];                                                                        \
    _Pragma("unroll")                                                                   \
    for (int m = 0; m < 4; ++m)                                                         \
        a3[m] = *(const s16x8*)(Ab + (wm * 128 + (4 + m) * 16 + fr) * 128 + cb1);       \
    __builtin_amdgcn_s_barrier();                                                       \
    /* phase 3: cvt+write B(t+1) in the shadow, then MFMA */                            \
    if (stA) { CVTW(RW, NXT); }                                                         \
    __builtin_amdgcn_s_setprio(1);                                                      \
    _Pragma("unroll")                                                                   \
    for (int m = 0; m < 4; ++m)                                                         \
        _Pragma("unroll")                                                               \
        for (int n = 0; n < 4; ++n)                                                     \
            acc[4 + m][n] = __builtin_amdgcn_mfma_f32_16x16x32_bf16(a3[m], b1[n], acc[4 + m][n], 0, 0, 0); \
    __builtin_amdgcn_s_setprio(0);                                                      \
    asm volatile("s_waitcnt lgkmcnt(0)" ::: "memory");                                  \
    __builtin_amdgcn_sched_barrier(0);                                                  \
    __builtin_amdgcn_s_barrier();                                                       \
  }

template<bool OUT_BF16>
__device__ __forceinline__ void gemm256_core(const u16* __restrict__ A,
                                             const float* __restrict__ Bpanel,
                                             void* __restrict__ C,
                                             int N, int K, int lda, int ldbf,
                                             int bm, int bn,
                                             u16 (&lds)[2][2][16384]) {
    int t = threadIdx.x;
    int lane = t & 63, wave = t >> 6;
    int wm = wave >> 2, wn = wave & 3;
    int fr = lane & 15, fq = lane >> 4;
    int sw = (fr & 7) << 4;

    // A staging (bf16, pre-swizzled source -> linear gload_lds dest)
    int srow = wave * 8 + (lane >> 3);
    int scb = ((lane & 7) * 16) ^ (((lane >> 3) & 7) << 4);
    const u16* aSrc = A + (size_t)(bm * 256 + srow) * lda + (scb >> 1);
    int ldsoff = wave * 512;   // elements

    // B reg-staging geometry (f32 -> bf16 LDS, write-swizzle == read-swizzle)
    int brow = wave * 8 + (lane >> 3);                       // row within 64-row unit
    const float* bSrcF = Bpanel + (size_t)brow * ldbf + (lane & 7) * 8;
    int bwb = brow * 128 + (((lane & 7) * 16) ^ ((brow & 7) << 4));   // dest byte in unit

    f32x4 acc[8][4];
    #pragma unroll
    for (int m = 0; m < 8; m++)
        #pragma unroll
        for (int n = 0; n < 4; n++)
            acc[m][n] = (f32x4){0.f, 0.f, 0.f, 0.f};

    float4 rE[4][2], rO[4][2];
    int nt = K >> 6;

    // prologue: LB(0)->rE, LB(1)->rO, A(0) stages; drain LB(0); write B(0) to buf0.
    LOADB(rE, 0);
    LOADB(rO, 1);
    STAGE_A(0, 0, 0); STAGE_A(0, 0, 1); STAGE_A(0, 0, 2); STAGE_A(0, 0, 3);
    __builtin_amdgcn_sched_barrier(0);
    asm volatile("s_waitcnt vmcnt(12)" ::: "memory");   // drains LB8(0); keeps LB8(1)+A4(0)
    CVTW(rE, 0);
    asm volatile("s_waitcnt lgkmcnt(0)" ::: "memory");
    __builtin_amdgcn_sched_barrier(0);

    for (int it = 0; it < nt; it += 2) {
        GTILE(0, 1, rE, rO, it);        // even tile: loads B(it+2)->rE, writes rO=B(it+1)->buf1
        GTILE(1, 0, rO, rE, it + 1);    // odd tile:  loads B(it+3)->rO, writes rE=B(it+2)->buf0
    }

    #pragma unroll
    for (int m = 0; m < 8; ++m) {
        int row = bm * 256 + wm * 128 + m * 16 + fq * 4;
        #pragma unroll
        for (int n = 0; n < 4; ++n) {
            int col = bn * 256 + wn * 64 + n * 16 + fr;
            #pragma unroll
            for (int r = 0; r < 4; ++r) {
                if (OUT_BF16) ((u16*)C)[(size_t)(row + r) * N + col] = f2bf(acc[m][n][r]);
                else          ((float*)C)[(size_t)(row + r) * N + col] = acc[m][n][r];
            }
        }
    }
}

// QKV GEMM: M=2048,N=8192,K=4608; B panels from wq/wk/wv f32 directly. grid 256.
__global__ __launch_bounds__(512) void gemm256_qkv(const u16* __restrict__ A,
                                                   const float* __restrict__ wq,
                                                   const float* __restrict__ wk,
                                                   const float* __restrict__ wv,
                                                   u16* __restrict__ C, int K) {
    __shared__ u16 lds[2][2][16384];
    int bid = blockIdx.x;
    int x = bid & 7, j = bid >> 3;
    int bn = x * 4 + (j & 3);     // XCD column-stripe
    int bm = j >> 2;
    const float* Bp;
    if (bn < 16)      Bp = wq + (size_t)bn * 256 * K;
    else if (bn < 24) Bp = wk + (size_t)(bn - 16) * 256 * K;
    else              Bp = wv + (size_t)(bn - 24) * 256 * K;
    gemm256_core<true>(A, Bp, C, 8192, K, K, K, bm, bn, lds);
}

// out-proj GEMM: M=2048,N=4608,K=4096, full K, f32 store. grid 144 (8 XCD-chunks of 18).
// A (=Ob) padded to LDO; B = wo f32 direct (stride 4096).
__global__ __launch_bounds__(512) void gemm256_out(const u16* __restrict__ A,
                                                   const float* __restrict__ wo,
                                                   float* __restrict__ C, int K) {
    __shared__ u16 lds[2][2][16384];
    int bid = blockIdx.x;
    int j = (bid & 7) * 18 + (bid >> 3);   // 144 = 8 XCD-chunks of 18
    int bm = j & 7;
    int bn = j >> 3;                       // 0..17
    gemm256_core<false>(A, wo + (size_t)bn * 256 * K, C, 4608, K, LDO, K, bm, bn, lds);
}

// ---------------- flash attention: 4 waves/block, fixed-max softmax ----------------
// Softcap bounds scores to +-50 -> fixed shift m=50:
//   p = exp2(-144.2695041 * rcp(exp2(0.05770780163*s) + 1))
__global__ __launch_bounds__(256) void attn_kernel(const u16* __restrict__ Qb,
                                                   const u16* __restrict__ Kb,
                                                   const u16* __restrict__ Vt,
                                                   u16* __restrict__ Ob) {
    __shared__ u16 Ks[64 * 128];    // 16 KB, swizzled
    __shared__ u16 Vs[128 * 64];    // 16 KB, swizzled
    __shared__ u16 Pst[4 * 1024];   // 2 KB per wave

    int bid = blockIdx.x;
    int hq = bid & 31;
    int qb = 31 - (bid >> 5);       // heavy blocks first
    int g = hq >> 1;
    int t = threadIdx.x;
    int lane = t & 63, wave = t >> 6;
    int fr = lane & 15, fq = lane >> 4;
    int sw = (fr & 7) << 4;
    int qrow0 = qb * 64 + wave * 16;
    u16* Pw = &Pst[wave * 1024];

    s16x8 qf[4];
    #pragma unroll
    for (int s = 0; s < 4; s++)
        qf[s] = *(const s16x8*)&Qb[(size_t)(qrow0 + fr) * 4096 + hq * 128 + s * 32 + fq * 8];

    f32x4 o[8];
    #pragma unroll
    for (int c = 0; c < 8; c++) o[c] = (f32x4){0.f, 0.f, 0.f, 0.f};
    float liacc[4] = {0.f, 0.f, 0.f, 0.f};

    int w4 = wave * 4;
    int nT = qb + 1;
    for (int kt = 0; kt < nT; kt++) {
        int kv0 = kt << 6;
        __syncthreads();
        #pragma unroll
        for (int i = 0; i < 4; i++) {
            int li_ = w4 + i;
            int rk = li_ * 4 + (lane >> 4);
            int cbk = ((lane & 15) * 16) ^ ((rk & 7) << 4);
            const u16* srcK = Kb + (size_t)(kv0 + rk) * 2048 + g * 128 + (cbk >> 1);
            __builtin_amdgcn_global_load_lds(
                (const __attribute__((address_space(1))) unsigned int*)srcK,
                (__attribute__((address_space(3))) unsigned int*)(Ks + li_ * 512), 16, 0, 0);
            int rv = li_ * 8 + (lane >> 3);
            int cbv = ((lane & 7) * 16) ^ ((rv & 7) << 4);
            const u16* srcV = Vt + (size_t)(g * 128 + rv) * 2048 + kv0 + (cbv >> 1);
            __builtin_amdgcn_global_load_lds(
                (const __attribute__((address_space(1))) unsigned int*)srcV,
                (__attribute__((address_space(3))) unsigned int*)(Vs + li_ * 512), 16, 0, 0);
        }
        __syncthreads();

        if (kv0 <= qrow0 + 15) {
            // ---- QK^T ----
            f32x4 sf[4];
            #pragma unroll
            for (int j = 0; j < 4; j++) sf[j] = (f32x4){0.f, 0.f, 0.f, 0.f};
            #pragma unroll
            for (int j = 0; j < 4; j++)
                #pragma unroll
                for (int s = 0; s < 4; s++) {
                    s16x8 kf = *(const s16x8*)&Ks[(j * 16 + fr) * 128 + (((s * 64 + fq * 16) ^ sw) >> 1)];
                    sf[j] = __builtin_amdgcn_mfma_f32_16x16x32_bf16(qf[s], kf, sf[j], 0, 0, 0);
                }
            // ---- fixed-max softcap softmax ----
            #pragma unroll
            for (int j = 0; j < 4; j++)
                #pragma unroll
                for (int r = 0; r < 4; r++) {
                    float s_ = sf[j][r];
                    float e = __builtin_amdgcn_exp2f(s_ * 0.05770780163f);
                    float p = __builtin_amdgcn_exp2f(-144.2695041f * __builtin_amdgcn_rcpf(e + 1.0f));
                    int colk = kv0 + j * 16 + fr;
                    int rowq = qrow0 + fq * 4 + r;
                    p = (colk > rowq) ? 0.0f : p;
                    sf[j][r] = p;
                    liacc[r] += p;
                }
            // ---- P -> LDS (bf16, swizzled, per-wave buffer) ----
            #pragma unroll
            for (int j = 0; j < 4; j++)
                #pragma unroll
                for (int r = 0; r < 4; r++) {
                    int row = fq * 4 + r, col = j * 16 + fr;
                    int byteoff = (row * 128 + col * 2) ^ ((row & 7) << 4);
                    *(u16*)((char*)Pw + byteoff) = f2bf(sf[j][r]);
                }
            // ---- PV ----
            #pragma unroll
            for (int s = 0; s < 2; s++) {
                int rbyte = (fr * 128 + s * 64 + fq * 16) ^ sw;
                s16x8 pf = *(const s16x8*)((const char*)Pw + rbyte);
                #pragma unroll
                for (int c = 0; c < 8; c++) {
                    s16x8 vf = *(const s16x8*)&Vs[(c * 16 + fr) * 64 + (((s * 64 + fq * 16) ^ sw) >> 1)];
                    o[c] = __builtin_amdgcn_mfma_f32_16x16x32_bf16(pf, vf, o[c], 0, 0, 0);
                }
            }
        }
    }
    // final row-sum reduce across the 16 lanes of each fq group
    #pragma unroll
    for (int d = 1; d < 16; d <<= 1)
        #pragma unroll
        for (int r = 0; r < 4; r++)
            liacc[r] += __shfl_xor(liacc[r], d);
    float rli[4];
    #pragma unroll
    for (int r = 0; r < 4; r++) rli[r] = __builtin_amdgcn_rcpf(liacc[r]);
    #pragma unroll
    for (int c = 0; c < 8; c++)
        #pragma unroll
        for (int r = 0; r < 4; r++) {
            int rowq = qrow0 + fq * 4 + r;
            Ob[(size_t)rowq * LDO + hq * 128 + c * 16 + fr] = f2bf(o[c][r] * rli[r]);
        }
}

extern "C" void kernel_launch(void* const* d_in, const int* in_sizes, int n_in,
                              void* d_out, int out_size, void* d_ws, size_t ws_size,
                              hipStream_t stream) {
    const float* x  = (const float*)d_in[0];
    // d_in[1] = mask (unused; causal computed directly)
    const float* wq = (const float*)d_in[2];
    const float* wk = (const float*)d_in[3];
    const float* wv = (const float*)d_in[4];
    const float* wo = (const float*)d_in[5];
    float* out = (float*)d_out;

    char* w = (char*)d_ws;
    u16*   xb   = (u16*)(w);                    // 2048*4608 bf16       = 18,874,368
    u16*   T16  = (u16*)(w + 18874368);         // 2048*8192 bf16       = 33,554,432
    u16*   Ob   = (u16*)(w + 52428800);         // 2048*4128 bf16       = 16,908,288
    u16*   Qbuf = (u16*)(w + 69337088);         // 2048*4096 bf16       = 16,777,216
    u16*   Kbuf = (u16*)(w + 86114304);         // 2048*2048 bf16       =  8,388,608
    u16*   Vt   = (u16*)(w + 94502912);         // 2048*2048 bf16       =  8,388,608
    float* cosT = (float*)(w + 102891520);      // 2048*64 f32          =    524,288
    float* sinT = (float*)(w + 103415808);      // end 103,940,096

    // rope tables + input cast (weights consumed as f32 by the GEMMs directly)
    rope_table_kernel<<<512, 256, 0, stream>>>(cosT, sinT);
    cast_kernel<<<9216, 256, 0, stream>>>(x, xb);

    // fused QKV GEMM: (2048 x 8192, K=4608), bf16 out, f32 weights, 256 blocks
    gemm256_qkv<<<256, 512, 0, stream>>>(xb, wq, wk, wv, T16, 4608);

    // epilogues (read bf16)
    rope_q_kernel<<<16384, 256, 0, stream>>>(T16, Qbuf, cosT, sinT);
    rope_k_kernel<<<8192, 256, 0, stream>>>(T16, Kbuf, cosT, sinT);
    vtrans_kernel<<<4096, 256, 0, stream>>>(T16, Vt);

    // attention (writes Ob with padded stride LDO)
    attn_kernel<<<1024, 256, 0, stream>>>(Qbuf, Kbuf, Vt, Ob);

    // out = attn @ wo^T (2048 x 4608, K=4096), full K, grid 144, f32 weights
    gemm256_out<<<144, 512, 0, stream>>>(Ob, wo, out, 4096);
}

// Round 15
// 394.391 us; speedup vs baseline: 2.8299x; 2.8299x over previous
//
#include <hip/hip_runtime.h>
#include <hip/hip_bf16.h>
#include <math.h>

typedef unsigned short u16;
typedef __attribute__((ext_vector_type(8))) short s16x8;
typedef __attribute__((ext_vector_type(4))) float f32x4;

#define SCALE 0.083333333333333329f   // 1/sqrt(144)
#define LDO 4128                      // padded Ob row stride (breaks 8KB pow2 aliasing)

__device__ __forceinline__ u16 f2bf(float f) {
    unsigned u = __float_as_uint(f);
    unsigned r = 0x7fffu + ((u >> 16) & 1u);
    return (u16)((u + r) >> 16);
}
__device__ __forceinline__ float bf2f(u16 v) {
    return __uint_as_float(((unsigned)v) << 16);
}

// ---------------- cast fp32 -> bf16 (vectorized) ----------------
__global__ __launch_bounds__(256) void cast_kernel(const float* __restrict__ in,
                                                   u16* __restrict__ out) {
    size_t i = ((size_t)blockIdx.x * 256 + threadIdx.x) * 4;
    float4 v = *(const float4*)(in + i);
    ushort4 o;
    o.x = f2bf(v.x); o.y = f2bf(v.y); o.z = f2bf(v.z); o.w = f2bf(v.w);
    *(ushort4*)(out + i) = o;
}

// ---------------- cast fp32 -> bf16 with padded output stride (4096 -> 4128) ----------------
__global__ __launch_bounds__(256) void cast_pad_kernel(const float* __restrict__ in,
                                                       u16* __restrict__ out) {
    size_t i = ((size_t)blockIdx.x * 256 + threadIdx.x) * 4;   // over rows x 4096
    size_t row = i >> 12;
    int col = (int)(i & 4095);
    float4 v = *(const float4*)(in + i);
    ushort4 o;
    o.x = f2bf(v.x); o.y = f2bf(v.y); o.z = f2bf(v.z); o.w = f2bf(v.w);
    *(ushort4*)(out + row * LDO + col) = o;
}

// ---------------- rope cos/sin table ----------------
__global__ __launch_bounds__(256) void rope_table_kernel(float* __restrict__ cosT,
                                                         float* __restrict__ sinT) {
    int idx = blockIdx.x * 256 + threadIdx.x;   // L*64
    int i = idx & 63, pos = idx >> 6;
    float inv = __expf(-((float)i / 64.0f) * 9.210340371976184f); // 10000^(-i/64)
    float ang = (float)pos * inv;
    cosT[idx] = cosf(ang);
    sinT[idx] = sinf(ang);
}

// ---------------- rope for Q (vectorized x4): T16 cols 0..4095 -> Qbuf ----------------
__global__ __launch_bounds__(256) void rope_q_kernel(const u16* __restrict__ T16,
                                                     u16* __restrict__ Qb,
                                                     const float* __restrict__ cosT,
                                                     const float* __restrict__ sinT) {
    int idx = blockIdx.x * 256 + threadIdx.x;   // L*32*16
    int i4 = (idx & 15) << 2;
    int head = (idx >> 4) & 31;
    int pos = idx >> 9;
    size_t rbase = (size_t)pos * 8192 + head * 128 + i4;
    ushort4 t1v = *(const ushort4*)&T16[rbase];
    ushort4 t2v = *(const ushort4*)&T16[rbase + 64];
    float4 cv = *(const float4*)&cosT[(pos << 6) + i4];
    float4 sv = *(const float4*)&sinT[(pos << 6) + i4];
    ushort4 o1, o2;
    {
        float t1 = bf2f(t1v.x), t2 = bf2f(t2v.x);
        o1.x = f2bf((t1 * cv.x - t2 * sv.x) * SCALE);
        o2.x = f2bf((t2 * cv.x + t1 * sv.x) * SCALE);
    }
    {
        float t1 = bf2f(t1v.y), t2 = bf2f(t2v.y);
        o1.y = f2bf((t1 * cv.y - t2 * sv.y) * SCALE);
        o2.y = f2bf((t2 * cv.y + t1 * sv.y) * SCALE);
    }
    {
        float t1 = bf2f(t1v.z), t2 = bf2f(t2v.z);
        o1.z = f2bf((t1 * cv.z - t2 * sv.z) * SCALE);
        o2.z = f2bf((t2 * cv.z + t1 * sv.z) * SCALE);
    }
    {
        float t1 = bf2f(t1v.w), t2 = bf2f(t2v.w);
        o1.w = f2bf((t1 * cv.w - t2 * sv.w) * SCALE);
        o2.w = f2bf((t2 * cv.w + t1 * sv.w) * SCALE);
    }
    size_t wbase = (size_t)pos * 4096 + head * 128 + i4;
    *(ushort4*)&Qb[wbase]      = o1;
    *(ushort4*)&Qb[wbase + 64] = o2;
}

// ---------------- rope for K (vectorized x4): T16 cols 4096..6143 -> Kbuf ----------------
__global__ __launch_bounds__(256) void rope_k_kernel(const u16* __restrict__ T16,
                                                     u16* __restrict__ Kb,
                                                     const float* __restrict__ cosT,
                                                     const float* __restrict__ sinT) {
    int idx = blockIdx.x * 256 + threadIdx.x;   // L*16*16
    int i4 = (idx & 15) << 2;
    int head = (idx >> 4) & 15;
    int pos = idx >> 8;
    size_t rbase = (size_t)pos * 8192 + 4096 + head * 128 + i4;
    ushort4 t1v = *(const ushort4*)&T16[rbase];
    ushort4 t2v = *(const ushort4*)&T16[rbase + 64];
    float4 cv = *(const float4*)&cosT[(pos << 6) + i4];
    float4 sv = *(const float4*)&sinT[(pos << 6) + i4];
    ushort4 o1, o2;
    {
        float t1 = bf2f(t1v.x), t2 = bf2f(t2v.x);
        o1.x = f2bf(t1 * cv.x - t2 * sv.x);
        o2.x = f2bf(t2 * cv.x + t1 * sv.x);
    }
    {
        float t1 = bf2f(t1v.y), t2 = bf2f(t2v.y);
        o1.y = f2bf(t1 * cv.y - t2 * sv.y);
        o2.y = f2bf(t2 * cv.y + t1 * sv.y);
    }
    {
        float t1 = bf2f(t1v.z), t2 = bf2f(t2v.z);
        o1.z = f2bf(t1 * cv.z - t2 * sv.z);
        o2.z = f2bf(t2 * cv.z + t1 * sv.z);
    }
    {
        float t1 = bf2f(t1v.w), t2 = bf2f(t2v.w);
        o1.w = f2bf(t1 * cv.w - t2 * sv.w);
        o2.w = f2bf(t2 * cv.w + t1 * sv.w);
    }
    size_t wbase = (size_t)pos * 2048 + head * 128 + i4;
    *(ushort4*)&Kb[wbase]      = o1;
    *(ushort4*)&Kb[wbase + 64] = o2;
}

// ---------------- V transpose (vectorized): T16 cols 6144..8191 -> Vt [2048][2048] ----------------
// 64x64 tiles, 256 thr. Global read/write ushort4; LDS scalar with +1 pad.
__global__ __launch_bounds__(256) void vtrans_kernel(const u16* __restrict__ T16,
                                                     u16* __restrict__ Vt) {
    __shared__ u16 tile[64][65];
    int bc = (blockIdx.x & 31) << 6;    // col within V block (0..2047)
    int bl = (blockIdx.x >> 5) << 6;    // row (l) tile
    int tx = threadIdx.x & 15, ty = threadIdx.x >> 4;   // 16 x 16
    #pragma unroll
    for (int rr = 0; rr < 4; rr++) {
        int row = rr * 16 + ty;
        ushort4 v = *(const ushort4*)&T16[(size_t)(bl + row) * 8192 + 6144 + bc + tx * 4];
        tile[row][tx * 4 + 0] = v.x;
        tile[row][tx * 4 + 1] = v.y;
        tile[row][tx * 4 + 2] = v.z;
        tile[row][tx * 4 + 3] = v.w;
    }
    __syncthreads();
    #pragma unroll
    for (int cc = 0; cc < 4; cc++) {
        int col = cc * 16 + ty;
        int l0 = tx * 4;
        ushort4 g;
        g.x = tile[l0 + 0][col];
        g.y = tile[l0 + 1][col];
        g.z = tile[l0 + 2][col];
        g.w = tile[l0 + 3][col];
        *(ushort4*)&Vt[(size_t)(bc + col) * 2048 + bl + l0] = g;
    }
}

// ============ 256x256 8-wave 4-phase GEMM, single-wait + hoisted ds_reads ============
// (round-13 proven structure, verbatim)
#define STAGE_A(buf, ktt, l)                                                            \
    __builtin_amdgcn_global_load_lds(                                                   \
        (const __attribute__((address_space(1))) unsigned int*)(aSrc + (size_t)(ktt) * 64 + (size_t)(l) * 64 * lda), \
        (__attribute__((address_space(3))) unsigned int*)(&lds[buf][0][(l) * 4096 + ldsoff]), 16, 0, 0)
#define STAGE_B(buf, ktt, l)                                                            \
    __builtin_amdgcn_global_load_lds(                                                   \
        (const __attribute__((address_space(1))) unsigned int*)(bSrc + (size_t)(ktt) * 64 + (size_t)(l) * 64 * ldb), \
        (__attribute__((address_space(3))) unsigned int*)(&lds[buf][1][(l) * 4096 + ldsoff]), 16, 0, 0)

template<bool OUT_BF16>
__device__ __forceinline__ void gemm256_core(const u16* __restrict__ A,
                                             const u16* __restrict__ B,
                                             void* __restrict__ C,
                                             int N, int K, int lda, int ldb,
                                             int bm, int bn,
                                             u16 (&lds)[2][2][16384]) {
    int t = threadIdx.x;
    int lane = t & 63, wave = t >> 6;
    int wm = wave >> 2, wn = wave & 3;
    int fr = lane & 15, fq = lane >> 4;
    int sw = (fr & 7) << 4;

    int srow = wave * 8 + (lane >> 3);
    int scb = ((lane & 7) * 16) ^ (((lane >> 3) & 7) << 4);   // pre-swizzled src col byte
    const u16* aSrc = A + (size_t)(bm * 256 + srow) * lda + (scb >> 1);
    const u16* bSrc = B + (size_t)(bn * 256 + srow) * ldb + (scb >> 1);
    int ldsoff = wave * 512;   // elements

    f32x4 acc[8][4];
    #pragma unroll
    for (int m = 0; m < 8; m++)
        #pragma unroll
        for (int n = 0; n < 4; n++)
            acc[m][n] = (f32x4){0.f, 0.f, 0.f, 0.f};

    // prologue: stage tile 0 fully into buf 0
    STAGE_B(0, 0, 0); STAGE_B(0, 0, 1); STAGE_B(0, 0, 2); STAGE_B(0, 0, 3);
    STAGE_A(0, 0, 0); STAGE_A(0, 0, 1); STAGE_A(0, 0, 2); STAGE_A(0, 0, 3);

    int nt = K >> 6;
    for (int it = 0; it < nt; ++it) {
        int cur = it & 1, nxt = cur ^ 1;
        bool more = (it + 1 < nt);
        const char* Ab = (const char*)&lds[cur][0][0];
        const char* Bb = (const char*)&lds[cur][1][0];
        int cb0 = (fq * 16) ^ sw;
        int cb1 = (64 + fq * 16) ^ sw;

        // ---- phase 0 ----
        if (more) {
            STAGE_B(nxt, it + 1, 0); STAGE_B(nxt, it + 1, 1);
            __builtin_amdgcn_sched_barrier(0);
            asm volatile("s_waitcnt vmcnt(2)" ::: "memory");   // all of tile t landed
        } else {
            asm volatile("s_waitcnt vmcnt(0)" ::: "memory");
        }
        __builtin_amdgcn_s_barrier();   // buf[cur] visible to all waves
        s16x8 b0[4], a0[4];
        #pragma unroll
        for (int n = 0; n < 4; ++n)
            b0[n] = *(const s16x8*)(Bb + (wn * 64 + n * 16 + fr) * 128 + cb0);
        #pragma unroll
        for (int m = 0; m < 4; ++m)
            a0[m] = *(const s16x8*)(Ab + (wm * 128 + m * 16 + fr) * 128 + cb0);
        __builtin_amdgcn_s_setprio(1);
        #pragma unroll
        for (int m = 0; m < 4; ++m)
            #pragma unroll
            for (int n = 0; n < 4; ++n)
                acc[m][n] = __builtin_amdgcn_mfma_f32_16x16x32_bf16(a0[m], b0[n], acc[m][n], 0, 0, 0);
        __builtin_amdgcn_s_setprio(0);
        s16x8 a1[4];   // hoisted P1 frags (tile t fully landed -> safe)
        #pragma unroll
        for (int m = 0; m < 4; ++m)
            a1[m] = *(const s16x8*)(Ab + (wm * 128 + (4 + m) * 16 + fr) * 128 + cb0);
        __builtin_amdgcn_s_barrier();

        // ---- phase 1 ----
        if (more) { STAGE_B(nxt, it + 1, 2); STAGE_B(nxt, it + 1, 3); }
        __builtin_amdgcn_s_setprio(1);
        #pragma unroll
        for (int m = 0; m < 4; ++m)
            #pragma unroll
            for (int n = 0; n < 4; ++n)
                acc[4 + m][n] = __builtin_amdgcn_mfma_f32_16x16x32_bf16(a1[m], b0[n], acc[4 + m][n], 0, 0, 0);
        __builtin_amdgcn_s_setprio(0);
        s16x8 b1[4], a2[4];   // hoisted P2 frags
        #pragma unroll
        for (int n = 0; n < 4; ++n)
            b1[n] = *(const s16x8*)(Bb + (wn * 64 + n * 16 + fr) * 128 + cb1);
        #pragma unroll
        for (int m = 0; m < 4; ++m)
            a2[m] = *(const s16x8*)(Ab + (wm * 128 + m * 16 + fr) * 128 + cb1);
        __builtin_amdgcn_s_barrier();

        // ---- phase 2 ----
        if (more) {
            STAGE_A(nxt, it + 1, 0); STAGE_A(nxt, it + 1, 1);
            STAGE_A(nxt, it + 1, 2); STAGE_A(nxt, it + 1, 3);
        }
        __builtin_amdgcn_s_setprio(1);
        #pragma unroll
        for (int m = 0; m < 4; ++m)
            #pragma unroll
            for (int n = 0; n < 4; ++n)
                acc[m][n] = __builtin_amdgcn_mfma_f32_16x16x32_bf16(a2[m], b1[n], acc[m][n], 0, 0, 0);
        __builtin_amdgcn_s_setprio(0);
        s16x8 a3[4];   // hoisted P3 frags
        #pragma unroll
        for (int m = 0; m < 4; ++m)
            a3[m] = *(const s16x8*)(Ab + (wm * 128 + (4 + m) * 16 + fr) * 128 + cb1);
        __builtin_amdgcn_s_barrier();

        // ---- phase 3 ----
        __builtin_amdgcn_s_setprio(1);
        #pragma unroll
        for (int m = 0; m < 4; ++m)
            #pragma unroll
            for (int n = 0; n < 4; ++n)
                acc[4 + m][n] = __builtin_amdgcn_mfma_f32_16x16x32_bf16(a3[m], b1[n], acc[4 + m][n], 0, 0, 0);
        __builtin_amdgcn_s_setprio(0);
        __builtin_amdgcn_s_barrier();   // end of tile: buf[cur] free for restage
    }

    #pragma unroll
    for (int m = 0; m < 8; ++m) {
        int row = bm * 256 + wm * 128 + m * 16 + fq * 4;
        #pragma unroll
        for (int n = 0; n < 4; ++n) {
            int col = bn * 256 + wn * 64 + n * 16 + fr;
            #pragma unroll
            for (int r = 0; r < 4; ++r) {
                if (OUT_BF16) ((u16*)C)[(size_t)(row + r) * N + col] = f2bf(acc[m][n][r]);
                else          ((float*)C)[(size_t)(row + r) * N + col] = acc[m][n][r];
            }
        }
    }
}

// QKV GEMM: M=2048,N=8192,K=4608, bf16 output. grid 256. XCD column-stripe.
__global__ __launch_bounds__(512) void gemm256_qkv(const u16* __restrict__ A,
                                                   const u16* __restrict__ B,
                                                   u16* __restrict__ C, int K) {
    __shared__ u16 lds[2][2][16384];
    int bid = blockIdx.x;
    int x = bid & 7, j = bid >> 3;
    int bn = x * 4 + (j & 3);
    int bm = j >> 2;
    gemm256_core<true>(A, B, C, 8192, K, K, K, bm, bn, lds);
}

// out-proj GEMM: M=2048,N=4608,K=4096, full K, f32 store. grid 144 (8 XCD-chunks of 18).
// A (=Ob) and B (=padded wo) have row stride LDO=4128 elements (8256 B, non-pow2).
__global__ __launch_bounds__(512) void gemm256_out(const u16* __restrict__ A,
                                                   const u16* __restrict__ B,
                                                   float* __restrict__ C, int K) {
    __shared__ u16 lds[2][2][16384];
    int bid = blockIdx.x;
    int j = (bid & 7) * 18 + (bid >> 3);   // 144 = 8 XCD-chunks of 18
    int bm = j & 7;
    int bn = j >> 3;                       // 0..17
    gemm256_core<false>(A, B, C, 4608, K, LDO, LDO, bm, bn, lds);
}

// ---------------- flash attention: 4 waves/block, fixed-max softmax ----------------
// Softcap bounds scores to +-50 -> fixed shift m=50:
//   p = exp2(-144.2695041 * rcp(exp2(0.05770780163*s) + 1))
__global__ __launch_bounds__(256) void attn_kernel(const u16* __restrict__ Qb,
                                                   const u16* __restrict__ Kb,
                                                   const u16* __restrict__ Vt,
                                                   u16* __restrict__ Ob) {
    __shared__ u16 Ks[64 * 128];    // 16 KB, swizzled
    __shared__ u16 Vs[128 * 64];    // 16 KB, swizzled
    __shared__ u16 Pst[4 * 1024];   // 2 KB per wave

    int bid = blockIdx.x;
    int hq = bid & 31;
    int qb = 31 - (bid >> 5);       // heavy blocks first
    int g = hq >> 1;
    int t = threadIdx.x;
    int lane = t & 63, wave = t >> 6;
    int fr = lane & 15, fq = lane >> 4;
    int sw = (fr & 7) << 4;
    int qrow0 = qb * 64 + wave * 16;
    u16* Pw = &Pst[wave * 1024];

    s16x8 qf[4];
    #pragma unroll
    for (int s = 0; s < 4; s++)
        qf[s] = *(const s16x8*)&Qb[(size_t)(qrow0 + fr) * 4096 + hq * 128 + s * 32 + fq * 8];

    f32x4 o[8];
    #pragma unroll
    for (int c = 0; c < 8; c++) o[c] = (f32x4){0.f, 0.f, 0.f, 0.f};
    float liacc[4] = {0.f, 0.f, 0.f, 0.f};

    int w4 = wave * 4;
    int nT = qb + 1;
    for (int kt = 0; kt < nT; kt++) {
        int kv0 = kt << 6;
        __syncthreads();
        #pragma unroll
        for (int i = 0; i < 4; i++) {
            int li_ = w4 + i;
            int rk = li_ * 4 + (lane >> 4);
            int cbk = ((lane & 15) * 16) ^ ((rk & 7) << 4);
            const u16* srcK = Kb + (size_t)(kv0 + rk) * 2048 + g * 128 + (cbk >> 1);
            __builtin_amdgcn_global_load_lds(
                (const __attribute__((address_space(1))) unsigned int*)srcK,
                (__attribute__((address_space(3))) unsigned int*)(Ks + li_ * 512), 16, 0, 0);
            int rv = li_ * 8 + (lane >> 3);
            int cbv = ((lane & 7) * 16) ^ ((rv & 7) << 4);
            const u16* srcV = Vt + (size_t)(g * 128 + rv) * 2048 + kv0 + (cbv >> 1);
            __builtin_amdgcn_global_load_lds(
                (const __attribute__((address_space(1))) unsigned int*)srcV,
                (__attribute__((address_space(3))) unsigned int*)(Vs + li_ * 512), 16, 0, 0);
        }
        __syncthreads();

        if (kv0 <= qrow0 + 15) {
            // ---- QK^T ----
            f32x4 sf[4];
            #pragma unroll
            for (int j = 0; j < 4; j++) sf[j] = (f32x4){0.f, 0.f, 0.f, 0.f};
            #pragma unroll
            for (int j = 0; j < 4; j++)
                #pragma unroll
                for (int s = 0; s < 4; s++) {
                    s16x8 kf = *(const s16x8*)&Ks[(j * 16 + fr) * 128 + (((s * 64 + fq * 16) ^ sw) >> 1)];
                    sf[j] = __builtin_amdgcn_mfma_f32_16x16x32_bf16(qf[s], kf, sf[j], 0, 0, 0);
                }
            // ---- fixed-max softcap softmax ----
            #pragma unroll
            for (int j = 0; j < 4; j++)
                #pragma unroll
                for (int r = 0; r < 4; r++) {
                    float s_ = sf[j][r];
                    float e = __builtin_amdgcn_exp2f(s_ * 0.05770780163f);
                    float p = __builtin_amdgcn_exp2f(-144.2695041f * __builtin_amdgcn_rcpf(e + 1.0f));
                    int colk = kv0 + j * 16 + fr;
                    int rowq = qrow0 + fq * 4 + r;
                    p = (colk > rowq) ? 0.0f : p;
                    sf[j][r] = p;
                    liacc[r] += p;
                }
            // ---- P -> LDS (bf16, swizzled, per-wave buffer) ----
            #pragma unroll
            for (int j = 0; j < 4; j++)
                #pragma unroll
                for (int r = 0; r < 4; r++) {
                    int row = fq * 4 + r, col = j * 16 + fr;
                    int byteoff = (row * 128 + col * 2) ^ ((row & 7) << 4);
                    *(u16*)((char*)Pw + byteoff) = f2bf(sf[j][r]);
                }
            // ---- PV ----
            #pragma unroll
            for (int s = 0; s < 2; s++) {
                int rbyte = (fr * 128 + s * 64 + fq * 16) ^ sw;
                s16x8 pf = *(const s16x8*)((const char*)Pw + rbyte);
                #pragma unroll
                for (int c = 0; c < 8; c++) {
                    s16x8 vf = *(const s16x8*)&Vs[(c * 16 + fr) * 64 + (((s * 64 + fq * 16) ^ sw) >> 1)];
                    o[c] = __builtin_amdgcn_mfma_f32_16x16x32_bf16(pf, vf, o[c], 0, 0, 0);
                }
            }
        }
    }
    // final row-sum reduce across the 16 lanes of each fq group
    #pragma unroll
    for (int d = 1; d < 16; d <<= 1)
        #pragma unroll
        for (int r = 0; r < 4; r++)
            liacc[r] += __shfl_xor(liacc[r], d);
    float rli[4];
    #pragma unroll
    for (int r = 0; r < 4; r++) rli[r] = __builtin_amdgcn_rcpf(liacc[r]);
    #pragma unroll
    for (int c = 0; c < 8; c++)
        #pragma unroll
        for (int r = 0; r < 4; r++) {
            int rowq = qrow0 + fq * 4 + r;
            Ob[(size_t)rowq * LDO + hq * 128 + c * 16 + fr] = f2bf(o[c][r] * rli[r]);
        }
}

extern "C" void kernel_launch(void* const* d_in, const int* in_sizes, int n_in,
                              void* d_out, int out_size, void* d_ws, size_t ws_size,
                              hipStream_t stream) {
    const float* x  = (const float*)d_in[0];
    // d_in[1] = mask (unused; causal computed directly)
    const float* wq = (const float*)d_in[2];
    const float* wk = (const float*)d_in[3];
    const float* wv = (const float*)d_in[4];
    const float* wo = (const float*)d_in[5];
    float* out = (float*)d_out;

    char* w = (char*)d_ws;
    u16*   xb   = (u16*)(w);                    // 2048*4608 bf16       = 18,874,368
    u16*   wb   = (u16*)(w + 18874368);         // 8192*4608 bf16       = 75,497,472
    u16*   T16  = (u16*)(w + 94371840);         // 2048*8192 bf16       = 33,554,432
    u16*   Ob   = (u16*)(w + 127926272);        // 2048*4128 bf16       = 16,908,288
    u16*   Qbuf = (u16*)(w + 144834560);        // 2048*4096 bf16       = 16,777,216
    u16*   Kbuf = (u16*)(w + 161611776);        // 2048*2048 bf16       =  8,388,608
    u16*   Vt   = (u16*)(w + 170000384);        // 2048*2048 bf16       =  8,388,608
    float* cosT = (float*)(w + 178388992);      // 2048*64 f32          =    524,288
    float* sinT = (float*)(w + 178913280);      // end 179,437,568

    // rope tables + input cast
    rope_table_kernel<<<512, 256, 0, stream>>>(cosT, sinT);
    cast_kernel<<<9216, 256, 0, stream>>>(x, xb);

    // fused QKV weights: wb rows [0,4096)=wq, [4096,6144)=wk, [6144,8192)=wv
    cast_kernel<<<18432, 256, 0, stream>>>(wq, wb);
    cast_kernel<<<9216, 256, 0, stream>>>(wk, wb + (size_t)4096 * 4608);
    cast_kernel<<<9216, 256, 0, stream>>>(wv, wb + (size_t)6144 * 4608);

    // fused QKV GEMM: (2048 x 8192, K=4608), bf16 out, 256 blocks x 512 thr
    gemm256_qkv<<<256, 512, 0, stream>>>(xb, wb, T16, 4608);

    // epilogues (vectorized ushort4)
    rope_q_kernel<<<4096, 256, 0, stream>>>(T16, Qbuf, cosT, sinT);
    rope_k_kernel<<<2048, 256, 0, stream>>>(T16, Kbuf, cosT, sinT);
    vtrans_kernel<<<1024, 256, 0, stream>>>(T16, Vt);

    // attention (writes Ob with padded stride LDO)
    attn_kernel<<<1024, 256, 0, stream>>>(Qbuf, Kbuf, Vt, Ob);

    // out = attn @ wo^T (2048 x 4608, K=4096), full K, grid 144, padded strides
    cast_pad_kernel<<<18432, 256, 0, stream>>>(wo, wb);
    gemm256_out<<<144, 512, 0, stream>>>(Ob, wb, out, 4096);
}